// Round 1
// baseline (254.523 us; speedup 1.0000x reference)
//
#include <hip/hip_runtime.h>
#include <math.h>

// Problem constants (CapsNet routing)
#define BB   256   // batch
#define NI   1152  // input capsules
#define DI   8     // input dim
#define NJ   10    // output capsules
#define DJ   16    // output dim
#define NCHUNK 18  // NI / CHUNK
#define CHUNK  64  // i per block
#define BG     32  // batch per block
#define NBG    8   // BB / BG

// ---------------------------------------------------------------------------
// k_s: spart[((b*NJ+j)*DJ+d)*NCHUNK + chunk] = sum_{i in chunk} c[b,j,i] *
//        (sum_k u[b,i,k] * W[j,i,d,k])
// Block = (j, i-chunk, batch-group). W fragment cached in registers per lane,
// reused across BG batch elements. u/c staged in LDS per b (broadcast reads).
// ---------------------------------------------------------------------------
__global__ __launch_bounds__(256) void k_s(const float* __restrict__ u,
                                           const float* __restrict__ W,
                                           const float* __restrict__ c,
                                           float* __restrict__ spart,
                                           int use_c) {
    int gx = blockIdx.x;
    int j     = gx % NJ;
    int chunk = (gx / NJ) % NCHUNK;
    int bg    = gx / (NJ * NCHUNK);
    int i0 = chunk * CHUNK;
    int b0 = bg * BG;
    int tid = threadIdx.x;
    int d = tid & 15;      // output dim handled by this lane
    int m = tid >> 4;      // i-group: lane covers i = m + 16*ii, ii=0..3

    __shared__ float us[CHUNK][DI];   // 2 KB
    __shared__ float cs[CHUNK];       // 256 B
    __shared__ float red[4][16];      // 256 B

    // W fragment: Wr[ii] = W[j, i0+m+16*ii, d, 0..7] (32 VGPRs), loaded once.
    float4 Wr[4][2];
#pragma unroll
    for (int ii = 0; ii < 4; ++ii) {
        const float4* wp = (const float4*)(W +
            (((size_t)j * NI + i0 + m + 16 * ii) * DJ + d) * DI);
        Wr[ii][0] = wp[0];
        Wr[ii][1] = wp[1];
    }

    for (int bb = 0; bb < BG; ++bb) {
        int b = b0 + bb;
        // stage u[b, i0..i0+63, :] (512 floats) and c[b, j, i0..i0+63]
        if (tid < 128) {
            const float4* up = (const float4*)(u + ((size_t)b * NI + i0) * DI);
            ((float4*)us)[tid] = up[tid];
        } else if (tid < 192) {
            int i = tid - 128;
            if (use_c)
                cs[i] = c[((size_t)b * NJ + j) * NI + i0 + i];
            else
                cs[i] = 0.1f;   // softmax of zeros over NJ=10
        }
        __syncthreads();

        float acc = 0.f;
#pragma unroll
        for (int ii = 0; ii < 4; ++ii) {
            int i = m + 16 * ii;
            const float4* up = (const float4*)&us[i][0];  // broadcast (16 lanes share i)
            float4 u0 = up[0], u1 = up[1];
            float dot = Wr[ii][0].x * u0.x + Wr[ii][0].y * u0.y +
                        Wr[ii][0].z * u0.z + Wr[ii][0].w * u0.w +
                        Wr[ii][1].x * u1.x + Wr[ii][1].y * u1.y +
                        Wr[ii][1].z * u1.z + Wr[ii][1].w * u1.w;
            acc += cs[i] * dot;
        }
        // reduce over the 16 i-groups: lanes with same d are tid = d + 16*m
        acc += __shfl_xor(acc, 16);
        acc += __shfl_xor(acc, 32);
        int lane = tid & 63, w = tid >> 6;
        if (lane < 16) red[w][d] = acc;
        __syncthreads();
        if (tid < 16) {
            float s = red[0][d] + red[1][d] + red[2][d] + red[3][d];
            spart[(((size_t)b * NJ + j) * DJ + d) * NCHUNK + chunk] = s;
        }
        // next iteration's __syncthreads (after staging) orders red/us reuse
    }
}

// ---------------------------------------------------------------------------
// k_b: bij[(b*NI+i)*NJ + j] (+)= sum_d v[b,j,d] * (sum_k u[b,i,k]*W[j,i,d,k])
// Same block decomposition and W-register layout as k_s; reduction is over
// the 16 d-lanes (contiguous within a wave) via shfl_xor 1,2,4,8.
// ---------------------------------------------------------------------------
__global__ __launch_bounds__(256) void k_b(const float* __restrict__ u,
                                           const float* __restrict__ W,
                                           const float* __restrict__ v,
                                           float* __restrict__ bij,
                                           int accum) {
    int gx = blockIdx.x;
    int j     = gx % NJ;
    int chunk = (gx / NJ) % NCHUNK;
    int bg    = gx / (NJ * NCHUNK);
    int i0 = chunk * CHUNK;
    int b0 = bg * BG;
    int tid = threadIdx.x;
    int d = tid & 15;
    int m = tid >> 4;

    __shared__ float us[CHUNK][DI];
    __shared__ float vs[DJ];

    float4 Wr[4][2];
#pragma unroll
    for (int ii = 0; ii < 4; ++ii) {
        const float4* wp = (const float4*)(W +
            (((size_t)j * NI + i0 + m + 16 * ii) * DJ + d) * DI);
        Wr[ii][0] = wp[0];
        Wr[ii][1] = wp[1];
    }

    for (int bb = 0; bb < BG; ++bb) {
        int b = b0 + bb;
        if (tid < 128) {
            const float4* up = (const float4*)(u + ((size_t)b * NI + i0) * DI);
            ((float4*)us)[tid] = up[tid];
        } else if (tid >= 128 && tid < 128 + DJ) {
            vs[tid - 128] = v[((size_t)b * NJ + j) * DJ + (tid - 128)];
        }
        __syncthreads();

        float vd = vs[d];
        float p[4];
#pragma unroll
        for (int ii = 0; ii < 4; ++ii) {
            int i = m + 16 * ii;
            const float4* up = (const float4*)&us[i][0];
            float4 u0 = up[0], u1 = up[1];
            float dot = Wr[ii][0].x * u0.x + Wr[ii][0].y * u0.y +
                        Wr[ii][0].z * u0.z + Wr[ii][0].w * u0.w +
                        Wr[ii][1].x * u1.x + Wr[ii][1].y * u1.y +
                        Wr[ii][1].z * u1.z + Wr[ii][1].w * u1.w;
            p[ii] = vd * dot;
        }
        // reduce over d (16 contiguous lanes within the wave)
#pragma unroll
        for (int s = 1; s <= 8; s <<= 1) {
#pragma unroll
            for (int ii = 0; ii < 4; ++ii) p[ii] += __shfl_xor(p[ii], s);
        }
        if (d == 0) {
#pragma unroll
            for (int ii = 0; ii < 4; ++ii) {
                int i = m + 16 * ii;
                size_t a = ((size_t)b * NI + i0 + i) * NJ + j;
                float val = p[ii];
                if (accum) val += bij[a];
                bij[a] = val;
            }
        }
        __syncthreads();  // protect us/vs before next stage
    }
}

// ---------------------------------------------------------------------------
// k_softmax: c[b,j,i] = softmax_j(bij[b,i,j])  (bij layout [b][i][j], j contig)
// ---------------------------------------------------------------------------
__global__ __launch_bounds__(256) void k_softmax(const float* __restrict__ bij,
                                                 float* __restrict__ c) {
    int idx = blockIdx.x * 256 + threadIdx.x;  // in [0, BB*NI)
    int b = idx / NI, i = idx - b * NI;
    const float* bp = bij + (size_t)idx * NJ;
    float x[NJ];
    float mx = -1e30f;
#pragma unroll
    for (int jj = 0; jj < NJ; ++jj) { x[jj] = bp[jj]; mx = fmaxf(mx, x[jj]); }
    float s = 0.f;
#pragma unroll
    for (int jj = 0; jj < NJ; ++jj) { x[jj] = __expf(x[jj] - mx); s += x[jj]; }
    float r = 1.f / s;
#pragma unroll
    for (int jj = 0; jj < NJ; ++jj)
        c[((size_t)b * NJ + jj) * NI + i] = x[jj] * r;
}

// ---------------------------------------------------------------------------
// k_v: reduce spart over chunks, squash, write v (and final output)
// ---------------------------------------------------------------------------
__global__ __launch_bounds__(256) void k_v(const float* __restrict__ spart,
                                           float* __restrict__ vout) {
    int idx = blockIdx.x * 256 + threadIdx.x;  // in [0, BB*NJ*DJ)
    const float* sp = spart + (size_t)idx * NCHUNK;
    float s = 0.f;
#pragma unroll
    for (int ch = 0; ch < NCHUNK; ++ch) s += sp[ch];
    float sq = s * s;
    // sum of squares over the 16 d-lanes (aligned groups within the wave)
#pragma unroll
    for (int del = 1; del <= 8; del <<= 1) sq += __shfl_xor(sq, del);
    float scale = (sq / (1.f + sq)) / sqrtf(sq + 1e-7f);
    vout[idx] = s * scale;
}

extern "C" void kernel_launch(void* const* d_in, const int* in_sizes, int n_in,
                              void* d_out, int out_size, void* d_ws, size_t ws_size,
                              hipStream_t stream) {
    const float* u = (const float*)d_in[0];   // (256,1152,8)
    const float* W = (const float*)d_in[1];   // (10,1152,16,8)
    float* out = (float*)d_out;               // (256,10,16)
    float* ws  = (float*)d_ws;

    float* bij   = ws;                                     // BB*NI*NJ  [b][i][j]
    float* c     = bij   + (size_t)BB * NI * NJ;           // BB*NJ*NI  [b][j][i]
    float* spart = c     + (size_t)BB * NJ * NI;           // BB*NJ*DJ*NCHUNK
    float* v     = spart + (size_t)BB * NJ * DJ * NCHUNK;  // BB*NJ*DJ

    dim3 blk(256);
    const int GRID_S = NJ * NCHUNK * NBG;    // 1440
    const int GRID_SM = (BB * NI) / 256;     // 1152
    const int GRID_V = (BB * NJ * DJ) / 256; // 160

    // t = 0 : c uniform 0.1 (softmax of zeros), b_ij written fresh (accum=0)
    k_s<<<GRID_S, blk, 0, stream>>>(u, W, c, spart, 0);
    k_v<<<GRID_V, blk, 0, stream>>>(spart, v);
    k_b<<<GRID_S, blk, 0, stream>>>(u, W, v, bij, 0);
    // t = 1
    k_softmax<<<GRID_SM, blk, 0, stream>>>(bij, c);
    k_s<<<GRID_S, blk, 0, stream>>>(u, W, c, spart, 1);
    k_v<<<GRID_V, blk, 0, stream>>>(spart, v);
    k_b<<<GRID_S, blk, 0, stream>>>(u, W, v, bij, 1);
    // t = 2 (final b-update unused by reference output)
    k_softmax<<<GRID_SM, blk, 0, stream>>>(bij, c);
    k_s<<<GRID_S, blk, 0, stream>>>(u, W, c, spart, 1);
    k_v<<<GRID_V, blk, 0, stream>>>(spart, out);
}

// Round 2
// 238.656 us; speedup vs baseline: 1.0665x; 1.0665x over previous
//
#include <hip/hip_runtime.h>
#include <math.h>

// Problem constants (CapsNet routing)
#define BB   256   // batch
#define NI   1152  // input capsules
#define DI   8     // input dim
#define NJ   10    // output capsules
#define DJ   16    // output dim
#define NCHUNK 18  // NI / CHUNK
#define CHUNK  64  // i per block
#define BG     32  // batch per block
#define NBG    8   // BB / BG

// XCD-bijective swizzle: 1440 blocks = 8 XCDs x 180. Hardware round-robins
// blockIdx.x % 8 -> XCD, so gx = (bid&7)*180 + (bid>>3) gives each XCD a
// contiguous gx range = one batch-group (u slice 1.2 MB -> L2-resident) and
// all (j, chunk).
__device__ __forceinline__ int swizzled_gx() {
    int bid = blockIdx.x;
    return (bid & 7) * (NJ * NCHUNK) + (bid >> 3);
}

// ---------------------------------------------------------------------------
// k_s: spart[((chunk*BB + b)*NJ + j)*DJ + d] =
//        sum_{i in chunk} c[b,j,i] * (sum_k u[b,i,k] * W[j,i,d,k])
// W fragment in registers (32 VGPR), reused over 32 b. u/c double-buffered in
// LDS with register prefetch (1 sync per b). Per-wave partials -> LDS, summed
// + written coalesced in the epilogue.
// ---------------------------------------------------------------------------
__global__ __launch_bounds__(256) void k_s(const float* __restrict__ u,
                                           const float* __restrict__ W,
                                           const float* __restrict__ c,
                                           float* __restrict__ spart,
                                           int use_c) {
    int gx = swizzled_gx();
    int j     = gx % NJ;
    int r     = gx / NJ;
    int chunk = r % NCHUNK;
    int bg    = r / NCHUNK;
    int i0 = chunk * CHUNK;
    int b0 = bg * BG;
    int tid = threadIdx.x;
    int d = tid & 15;      // output dim for this lane
    int m = tid >> 4;      // i-group: lane covers i = m + 16*ii

    __shared__ __align__(16) float us[2][CHUNK][DI];   // 4 KB
    __shared__ float cs[2][CHUNK];                     // 512 B
    __shared__ float sres[BG][4][DJ];                  // 8 KB [bb][wave][d]

    float4 Wr[4][2];
#pragma unroll
    for (int ii = 0; ii < 4; ++ii) {
        const float4* wp = (const float4*)(W +
            (((size_t)j * NI + i0 + m + 16 * ii) * DJ + d) * DI);
        Wr[ii][0] = wp[0];
        Wr[ii][1] = wp[1];
    }

    // stage b0
    if (tid < 128) {
        const float4* up = (const float4*)(u + ((size_t)b0 * NI + i0) * DI);
        ((float4*)us[0])[tid] = up[tid];
    } else if (tid < 192) {
        int i = tid - 128;
        cs[0][i] = use_c ? c[((size_t)b0 * NJ + j) * NI + i0 + i] : 0.1f;
    }
    __syncthreads();

    int lane = tid & 63, w = tid >> 6;
    for (int bb = 0; bb < BG; ++bb) {
        int cur = bb & 1, nxt = cur ^ 1;

        // prefetch b0+bb+1 into registers (overlaps with compute below)
        float4 pu; float pc = 0.1f;
        bool ldu = (bb + 1 < BG) && (tid < 128);
        bool ldc = (bb + 1 < BG) && (tid >= 128 && tid < 192);
        if (ldu) {
            const float4* up = (const float4*)(u + ((size_t)(b0 + bb + 1) * NI + i0) * DI);
            pu = up[tid];
        }
        if (ldc && use_c)
            pc = c[((size_t)(b0 + bb + 1) * NJ + j) * NI + i0 + (tid - 128)];

        float acc = 0.f;
#pragma unroll
        for (int ii = 0; ii < 4; ++ii) {
            int i = m + 16 * ii;
            const float4* up = (const float4*)&us[cur][i][0];  // 16-lane broadcast
            float4 u0 = up[0], u1 = up[1];
            float dot = Wr[ii][0].x * u0.x + Wr[ii][0].y * u0.y +
                        Wr[ii][0].z * u0.z + Wr[ii][0].w * u0.w +
                        Wr[ii][1].x * u1.x + Wr[ii][1].y * u1.y +
                        Wr[ii][1].z * u1.z + Wr[ii][1].w * u1.w;
            acc += cs[cur][i] * dot;
        }
        // reduce over the 4 i-groups within this wave
        acc += __shfl_xor(acc, 16);
        acc += __shfl_xor(acc, 32);
        if (lane < 16) sres[bb][w][d] = acc;

        if (ldu) ((float4*)us[nxt])[tid] = pu;
        if (ldc) cs[nxt][tid - 128] = pc;
        __syncthreads();
    }

    // epilogue: sum 4 wave-partials, coalesced write (64B per 16-lane group)
#pragma unroll
    for (int p = 0; p < 2; ++p) {
        int bb = (tid >> 4) + 16 * p;
        int dd = tid & 15;
        float s = sres[bb][0][dd] + sres[bb][1][dd] + sres[bb][2][dd] + sres[bb][3][dd];
        spart[(((size_t)chunk * BB + b0 + bb) * NJ + j) * DJ + dd] = s;
    }
}

// ---------------------------------------------------------------------------
// k_b: delta[(b*NJ + j)*NI + i] (+)= sum_d v[b,j,d] * (sum_k u[b,i,k]*W[j,i,d,k])
// Results accumulate in LDS bres[32][64]; epilogue does coalesced float4
// writes (RMW when accum) into the block's exclusive [b][j][i0:i0+64] region.
// ---------------------------------------------------------------------------
__global__ __launch_bounds__(256) void k_b(const float* __restrict__ u,
                                           const float* __restrict__ W,
                                           const float* __restrict__ v,
                                           float* __restrict__ delta,
                                           int accum) {
    int gx = swizzled_gx();
    int j     = gx % NJ;
    int r     = gx / NJ;
    int chunk = r % NCHUNK;
    int bg    = r / NCHUNK;
    int i0 = chunk * CHUNK;
    int b0 = bg * BG;
    int tid = threadIdx.x;
    int d = tid & 15;
    int m = tid >> 4;

    __shared__ __align__(16) float us[2][CHUNK][DI];   // 4 KB
    __shared__ float vsm[2][DJ];                       // 128 B
    __shared__ __align__(16) float bres[BG][CHUNK];    // 8 KB

    float4 Wr[4][2];
#pragma unroll
    for (int ii = 0; ii < 4; ++ii) {
        const float4* wp = (const float4*)(W +
            (((size_t)j * NI + i0 + m + 16 * ii) * DJ + d) * DI);
        Wr[ii][0] = wp[0];
        Wr[ii][1] = wp[1];
    }

    if (tid < 128) {
        const float4* up = (const float4*)(u + ((size_t)b0 * NI + i0) * DI);
        ((float4*)us[0])[tid] = up[tid];
    } else if (tid < 128 + DJ) {
        vsm[0][tid - 128] = v[((size_t)b0 * NJ + j) * DJ + (tid - 128)];
    }
    __syncthreads();

    for (int bb = 0; bb < BG; ++bb) {
        int cur = bb & 1, nxt = cur ^ 1;

        float4 pu; float pv;
        bool ldu = (bb + 1 < BG) && (tid < 128);
        bool ldv = (bb + 1 < BG) && (tid >= 128 && tid < 128 + DJ);
        if (ldu) {
            const float4* up = (const float4*)(u + ((size_t)(b0 + bb + 1) * NI + i0) * DI);
            pu = up[tid];
        }
        if (ldv)
            pv = v[((size_t)(b0 + bb + 1) * NJ + j) * DJ + (tid - 128)];

        float vd = vsm[cur][d];
        float p[4];
#pragma unroll
        for (int ii = 0; ii < 4; ++ii) {
            int i = m + 16 * ii;
            const float4* up = (const float4*)&us[cur][i][0];
            float4 u0 = up[0], u1 = up[1];
            float dot = Wr[ii][0].x * u0.x + Wr[ii][0].y * u0.y +
                        Wr[ii][0].z * u0.z + Wr[ii][0].w * u0.w +
                        Wr[ii][1].x * u1.x + Wr[ii][1].y * u1.y +
                        Wr[ii][1].z * u1.z + Wr[ii][1].w * u1.w;
            p[ii] = vd * dot;
        }
        // reduce over d (lane bits 0..3)
#pragma unroll
        for (int s = 1; s <= 8; s <<= 1) {
#pragma unroll
            for (int ii = 0; ii < 4; ++ii) p[ii] += __shfl_xor(p[ii], s);
        }
        if (d == 0) {
#pragma unroll
            for (int ii = 0; ii < 4; ++ii) bres[bb][m + 16 * ii] = p[ii];
        }

        if (ldu) ((float4*)us[nxt])[tid] = pu;
        if (ldv) vsm[nxt][tid - 128] = pv;
        __syncthreads();
    }

    // epilogue: coalesced float4 (RMW if accum) into exclusive region
#pragma unroll
    for (int p2 = 0; p2 < 2; ++p2) {
        int bb = (tid >> 4) + 16 * p2;
        int q  = tid & 15;
        float4 val = ((const float4*)bres[bb])[q];
        float* dst = delta + (((size_t)(b0 + bb) * NJ + j) * NI + i0) + q * 4;
        if (accum) {
            float4 old = *(const float4*)dst;
            val.x += old.x; val.y += old.y; val.z += old.z; val.w += old.w;
        }
        *(float4*)dst = val;
    }
}

// ---------------------------------------------------------------------------
// k_softmax: c[b,j,i] = softmax_j(delta[b,j,i])   (both [b][j][i], coalesced)
// ---------------------------------------------------------------------------
__global__ __launch_bounds__(256) void k_softmax(const float* __restrict__ delta,
                                                 float* __restrict__ c) {
    int idx = blockIdx.x * 256 + threadIdx.x;  // in [0, BB*NI)
    int b = idx / NI, i = idx - b * NI;
    float x[NJ];
    float mx = -1e30f;
#pragma unroll
    for (int jj = 0; jj < NJ; ++jj) {
        x[jj] = delta[((size_t)b * NJ + jj) * NI + i];
        mx = fmaxf(mx, x[jj]);
    }
    float s = 0.f;
#pragma unroll
    for (int jj = 0; jj < NJ; ++jj) { x[jj] = __expf(x[jj] - mx); s += x[jj]; }
    float rs = 1.f / s;
#pragma unroll
    for (int jj = 0; jj < NJ; ++jj)
        c[((size_t)b * NJ + jj) * NI + i] = x[jj] * rs;
}

// ---------------------------------------------------------------------------
// k_v: reduce spart over chunks (coalesced: chunk is the outer dim), squash
// ---------------------------------------------------------------------------
__global__ __launch_bounds__(256) void k_v(const float* __restrict__ spart,
                                           float* __restrict__ vout) {
    int idx = blockIdx.x * 256 + threadIdx.x;  // (b*NJ+j)*DJ+d, total 40960
    float s = 0.f;
#pragma unroll
    for (int ch = 0; ch < NCHUNK; ++ch)
        s += spart[(size_t)ch * (BB * NJ * DJ) + idx];
    float sq = s * s;
#pragma unroll
    for (int del = 1; del <= 8; del <<= 1) sq += __shfl_xor(sq, del);
    float scale = (sq / (1.f + sq)) / sqrtf(sq + 1e-7f);
    vout[idx] = s * scale;
}

extern "C" void kernel_launch(void* const* d_in, const int* in_sizes, int n_in,
                              void* d_out, int out_size, void* d_ws, size_t ws_size,
                              hipStream_t stream) {
    const float* u = (const float*)d_in[0];   // (256,1152,8)
    const float* W = (const float*)d_in[1];   // (10,1152,16,8)
    float* out = (float*)d_out;               // (256,10,16)
    float* ws  = (float*)d_ws;

    float* delta = ws;                                      // BB*NJ*NI  [b][j][i]
    float* c     = delta + (size_t)BB * NJ * NI;            // BB*NJ*NI  [b][j][i]
    float* spart = c     + (size_t)BB * NJ * NI;            // NCHUNK*BB*NJ*DJ
    float* v     = spart + (size_t)NCHUNK * BB * NJ * DJ;   // BB*NJ*DJ

    dim3 blk(256);
    const int GRID_S  = NJ * NCHUNK * NBG;    // 1440
    const int GRID_SM = (BB * NI) / 256;      // 1152
    const int GRID_V  = (BB * NJ * DJ) / 256; // 160

    // t = 0 : c uniform 0.1 (softmax of zeros); delta written fresh
    k_s<<<GRID_S, blk, 0, stream>>>(u, W, c, spart, 0);
    k_v<<<GRID_V, blk, 0, stream>>>(spart, v);
    k_b<<<GRID_S, blk, 0, stream>>>(u, W, v, delta, 0);
    // t = 1
    k_softmax<<<GRID_SM, blk, 0, stream>>>(delta, c);
    k_s<<<GRID_S, blk, 0, stream>>>(u, W, c, spart, 1);
    k_v<<<GRID_V, blk, 0, stream>>>(spart, v);
    k_b<<<GRID_S, blk, 0, stream>>>(u, W, v, delta, 1);
    // t = 2 (final b-update not needed for the output)
    k_softmax<<<GRID_SM, blk, 0, stream>>>(delta, c);
    k_s<<<GRID_S, blk, 0, stream>>>(u, W, c, spart, 1);
    k_v<<<GRID_V, blk, 0, stream>>>(spart, out);
}